// Round 9
// baseline (361.315 us; speedup 1.0000x reference)
//
#include <hip/hip_runtime.h>
#include <hip/hip_bf16.h>

// Problem constants
#define B_ROWS 16384
#define OBS_D  512
#define H_D    1024
#define N_AG   9

typedef __attribute__((ext_vector_type(8))) short short8;
typedef __attribute__((ext_vector_type(4))) float floatx4;

__device__ __forceinline__ unsigned short f_to_bf_raw(float f) {
  union { float f; unsigned u; } c; c.f = f;
  unsigned u = c.u;
  u = u + 0x7FFF + ((u >> 16) & 1);   // round-to-nearest-even
  return (unsigned short)(u >> 16);
}

// Fragment-major layout (identical for MFMA 16x16x32 A- and B-operands):
// element (row r, k) lives at
//   frag_tile = (r>>4)*KT + (k>>5)        (KT = K/32)
//   lane      = (r&15) | (((k>>3)&3)<<4)
//   j         = k&7
// offset (bf16 units) = (frag_tile*64 + lane)*8 + j
// -> a wave's frag load is base + lane*16: one coalesced 1KB dwordx4 line.
__device__ __forceinline__ size_t frag_off(int r, int k, int KT) {
  const int ft = (r >> 4) * KT + (k >> 5);
  const int ln = (r & 15) | (((k >> 3) & 3) << 4);
  return ((size_t)ft * 64 + ln) * 8 + (k & 7);
}

// ---------------------------------------------------------------------------
// Mega-prep: obs cast+frag-major, W1f/W2f/WHf (frag-major weights,
// WH = [Wc1|Wt1|Wk1fold]), bias2048/w2cat concat. Branch block-uniform.
// Grid: [0,4096) obs | [4096,4608) W1f | [4608,5632) W2f |
//       [5632,7680) WHf | [7680,7688) vecs
// ---------------------------------------------------------------------------
__global__ __launch_bounds__(256) void prep_all(
    const float* __restrict__ obs,
    const float* __restrict__ W1, const float* __restrict__ W2,
    const float* __restrict__ Wc1, const float* __restrict__ Wt1,
    const float* __restrict__ Wk1,
    const float* __restrict__ bc1, const float* __restrict__ bt1,
    const float* __restrict__ bk1,
    const float* __restrict__ Wc2, const float* __restrict__ Wt2,
    const float* __restrict__ Wk2,
    unsigned short* __restrict__ obs_f,
    unsigned short* __restrict__ W1f, unsigned short* __restrict__ W2f,
    unsigned short* __restrict__ WHf,
    float* __restrict__ bias2048, float* __restrict__ w2cat) {
  __shared__ float t[32][33];
  const int bx  = blockIdx.x;
  const int tid = threadIdx.x;

  if (bx < 4096) {            // obs fp32 -> bf16 frag-major (KT=16)
    const int id   = bx * 256 + tid;      // one (frag_tile, lane) per thread
    const int lane = id & 63;
    const int ft   = id >> 6;             // 0 .. 16384/16*16 - 1
    const int mt   = ft >> 4;             // m-tile (KT=16)
    const int kt   = ft & 15;
    const int m    = mt * 16 + (lane & 15);
    const int k0   = kt * 32 + (lane >> 4) * 8;
    float4 a = *(const float4*)(obs + (size_t)m * 512 + k0);
    float4 b = *(const float4*)(obs + (size_t)m * 512 + k0 + 4);
    short8 o;
    o[0] = (short)f_to_bf_raw(a.x); o[1] = (short)f_to_bf_raw(a.y);
    o[2] = (short)f_to_bf_raw(a.z); o[3] = (short)f_to_bf_raw(a.w);
    o[4] = (short)f_to_bf_raw(b.x); o[5] = (short)f_to_bf_raw(b.y);
    o[6] = (short)f_to_bf_raw(b.z); o[7] = (short)f_to_bf_raw(b.w);
    *(short8*)(obs_f + ((size_t)ft * 64 + lane) * 8) = o;   // coalesced 16B
    return;
  }

  const int tx = tid & 31;
  const int ty = tid >> 5;   // 0..7

  if (bx < 4608) {                       // W1 [512,1024] -> W1f (K=512,KT=16)
    const int tt = bx - 4096;
    const int k0 = (tt & 15) * 32;
    const int n0 = (tt >> 4) * 32;
#pragma unroll
    for (int i = ty; i < 32; i += 8)
      t[i][tx] = W1[(size_t)(k0 + i) * 1024 + n0 + tx];
    __syncthreads();
#pragma unroll
    for (int i = ty; i < 32; i += 8)
      W1f[frag_off(n0 + i, k0 + tx, 16)] = f_to_bf_raw(t[tx][i]);
    return;
  }

  if (bx < 5632) {                       // W2 [1024,1024] -> W2f (KT=32)
    const int tt = bx - 4608;
    const int k0 = (tt & 31) * 32;
    const int n0 = (tt >> 5) * 32;
#pragma unroll
    for (int i = ty; i < 32; i += 8)
      t[i][tx] = W2[(size_t)(k0 + i) * 1024 + n0 + tx];
    __syncthreads();
#pragma unroll
    for (int i = ty; i < 32; i += 8)
      W2f[frag_off(n0 + i, k0 + tx, 32)] = f_to_bf_raw(t[tx][i]);
    return;
  }

  if (bx < 7680) {                       // WHf [2048 n,1024 k] (KT=32)
    const int tt = bx - 5632;
    const int k0 = (tt & 31) * 32;
    const int n0 = (tt >> 5) * 32;       // region-uniform per block
#pragma unroll
    for (int i = ty; i < 32; i += 8) {
      const int n = n0 + tx;
      float v;
      if (n0 < 512)
        v = Wc1[(size_t)(k0 + i) * 512 + n];
      else if (n0 < 1024)
        v = Wt1[(size_t)(k0 + i) * 512 + (n - 512)];
      else
        v = Wk1[(size_t)(k0 + i) * 1024 + (n - 1024)]
          + Wk1[(size_t)(k0 + i + 1024) * 1024 + (n - 1024)];
      t[i][tx] = v;
    }
    __syncthreads();
#pragma unroll
    for (int i = ty; i < 32; i += 8)
      WHf[frag_off(n0 + i, k0 + tx, 32)] = f_to_bf_raw(t[tx][i]);
    return;
  }

  {                                      // bias2048 / w2cat
    int n = (bx - 7680) * 256 + tid;
    float b, w;
    if (n < 512)       { b = bc1[n];        w = Wc2[n]; }
    else if (n < 1024) { b = bt1[n - 512];  w = Wt2[n - 512]; }
    else               { b = bk1[n - 1024]; w = Wk2[n - 1024]; }
    bias2048[n] = b;
    w2cat[n] = w;
  }
}

// ===========================================================================
// GEMM core v8: BARRIER-FREE K-loop. Both A and B are frag-major in global;
// every frag load is one coalesced global_load_dwordx4 (base + lane*16).
// No LDS, no __syncthreads in the K-loop. Register prefetch distance 2
// (3 rotating sets; K constexpr -> full unroll -> all indices compile-time,
// round-6 lesson). Each wave independently hides its own load latency
// (~2 iters in flight) — no collective vmcnt(0) barrier stall (round-8
// diagnosis: per-iter wall 1900 cyc vs 180 cyc of work).
// XCD swizzle: blocks sharing a weight strip land on the same XCD
// (id&7 -> n-strip group) -> per-XCD L2 weight working set 0.5 MB.
// ===========================================================================
#define GEMM_CORE_V8(ACC_DECL)                                                 \
  const int tid  = threadIdx.x;                                                \
  const int lane = tid & 63;                                                   \
  const int wave = tid >> 6;                                                   \
  constexpr int nper = NT / 8;                                                 \
  const int xcd  = blockIdx.x & 7;                                             \
  const int rest = blockIdx.x >> 3;                                            \
  const int n_t  = xcd * nper + (rest % nper);                                 \
  const int m_t  = rest / nper;                                                \
  const int m0 = m_t * 128;                                                    \
  const int n0 = n_t * 128;                                                    \
  const int wm = (wave & 1) * 64;                                              \
  const int wn = (wave >> 1) * 64;                                             \
  const int fr = lane & 15;                                                    \
  const int fq = lane >> 4;                                                    \
  ACC_DECL;                                                                    \
  constexpr int KT = K >> 5;                                                   \
  const unsigned short* gA =                                                   \
      Af + ((size_t)(((m0 + wm) >> 4) * KT) * 64 + lane) * 8;                  \
  const unsigned short* gB =                                                   \
      Bf + ((size_t)(((n0 + wn) >> 4) * KT) * 64 + lane) * 8;                  \
  short8 Fa[3][4], Fb[3][4];                                                   \
  _Pragma("unroll")                                                            \
  for (int p = 0; p < 2; ++p) {                                                \
    _Pragma("unroll")                                                          \
    for (int mi = 0; mi < 4; ++mi)                                             \
      Fa[p][mi] = *(const short8*)(gA + ((size_t)mi * KT + p) * 512);          \
    _Pragma("unroll")                                                          \
    for (int ni = 0; ni < 4; ++ni)                                             \
      Fb[p][ni] = *(const short8*)(gB + ((size_t)ni * KT + p) * 512);          \
  }                                                                            \
  _Pragma("unroll")                                                            \
  for (int k = 0; k < KT; ++k) {        /* constexpr bound -> full unroll */   \
    const int cur = k % 3;                                                     \
    if (k + 2 < KT) {                                                          \
      const int nxt = (k + 2) % 3;                                             \
      _Pragma("unroll")                                                        \
      for (int mi = 0; mi < 4; ++mi)                                           \
        Fa[nxt][mi] = *(const short8*)(gA + ((size_t)mi * KT + k + 2) * 512);  \
      _Pragma("unroll")                                                        \
      for (int ni = 0; ni < 4; ++ni)                                           \
        Fb[nxt][ni] = *(const short8*)(gB + ((size_t)ni * KT + k + 2) * 512);  \
    }                                                                          \
    _Pragma("unroll")                                                          \
    for (int mi = 0; mi < 4; ++mi)                                             \
      _Pragma("unroll")                                                        \
      for (int ni = 0; ni < 4; ++ni)                                           \
        acc[mi][ni] = __builtin_amdgcn_mfma_f32_16x16x32_bf16(                 \
            Fa[cur][mi], Fb[cur][ni], acc[mi][ni], 0, 0, 0);                   \
  }

#define ACC_INIT                                                               \
  floatx4 acc[4][4];                                                           \
  _Pragma("unroll")                                                            \
  for (int i = 0; i < 4; ++i)                                                  \
    _Pragma("unroll")                                                          \
    for (int j = 0; j < 4; ++j) acc[i][j] = (floatx4){0.f, 0.f, 0.f, 0.f}

// ---------------------------------------------------------------------------
// Trunk GEMM: C = relu(A @ B^T + bias), OUTPUT IN FRAG-MAJOR (for the next
// GEMM's A operand, KT2 = N/32) via one-time LDS repack:
//  two passes over mi-halves; each pass: scatter bf16 to padded LDS
//  [64][136], sync, read consumer-frags (16B ds_read) and store coalesced
//  16B global. Pad 136 -> row stride 68 banks -> 2-way (free) on reads.
// ---------------------------------------------------------------------------
template <int K, int NT>
__global__ __launch_bounds__(256, 2) void gemm_bias_relu(
    const unsigned short* __restrict__ Af,
    const unsigned short* __restrict__ Bf,
    const float* __restrict__ bias,
    unsigned short* __restrict__ Cf) {
  GEMM_CORE_V8(ACC_INIT)

  constexpr int KT2 = (NT * 128) / 32;   // consumer K-tiles
  __shared__ unsigned short eps[64][136];
  float bv[4];
#pragma unroll
  for (int ni = 0; ni < 4; ++ni) bv[ni] = bias[n0 + wn + ni * 16 + fr];

#pragma unroll
  for (int p = 0; p < 2; ++p) {
    if (p) __syncthreads();
#pragma unroll
    for (int h = 0; h < 2; ++h) {        // mi = 2p + h
      const int mi = 2 * p + h;
#pragma unroll
      for (int ni = 0; ni < 4; ++ni) {
#pragma unroll
        for (int r = 0; r < 4; ++r) {
          float v = acc[mi][ni][r] + bv[ni];
          v = v > 0.f ? v : 0.f;
          eps[(wm >> 1) + h * 16 + fq * 4 + r][wn + ni * 16 + fr] =
              f_to_bf_raw(v);
        }
      }
    }
    __syncthreads();
    // read consumer-frags + coalesced 16B stores (4 slots/thread)
#pragma unroll
    for (int s = 0; s < 4; ++s) {
      const int slot = s * 4 + wave;     // 0..15
      const int tl   = slot >> 2;        // local m-tile 0..3
      const int ktl  = slot & 3;         // local k-chunk 0..3
      const int Lrow = tl * 16 + (lane & 15);
      const int ncol = ktl * 32 + (lane >> 4) * 8;
      short8 v = *(const short8*)&eps[Lrow][ncol];
      const int gmt = (m0 >> 4) + ((tl >> 1) * 4) + 2 * p + (tl & 1);
      const int gkt = (n0 >> 5) + ktl;
      *(short8*)(Cf + ((size_t)(gmt * KT2 + gkt) * 64 + lane) * 8) = v;
    }
  }
}

// ---------------------------------------------------------------------------
// Fused heads GEMM: relu(G @ WH^T + bias2048) dotted with w2cat in-register,
// non-atomic partials part[j][row], j = n_t*2 + wave_half in [0,32).
// j 0..7 coverage, 8..15 tracking, 16..31 cooperation. No LDS at all.
// ---------------------------------------------------------------------------
template <int K, int NT>
__global__ __launch_bounds__(256, 2) void gemm_heads_fused(
    const unsigned short* __restrict__ Af,   // G frag-major [B,1024]
    const unsigned short* __restrict__ Bf,   // WHf frag-major [2048,1024]
    const float* __restrict__ bias,          // bias2048
    const float* __restrict__ w2,            // w2cat
    float* __restrict__ part) {              // [32][B_ROWS]
  GEMM_CORE_V8(ACC_INIT)

  const int j = n_t * 2 + (wave >> 1);
  float w2v[4], bv[4];
#pragma unroll
  for (int ni = 0; ni < 4; ++ni) {
    const int gn = n0 + wn + ni * 16 + fr;
    w2v[ni] = w2[gn];
    bv[ni]  = bias[gn];
  }
#pragma unroll
  for (int mi = 0; mi < 4; ++mi) {
#pragma unroll
    for (int r = 0; r < 4; ++r) {
      float p = 0.f;
#pragma unroll
      for (int ni = 0; ni < 4; ++ni) {
        float v = acc[mi][ni][r] + bv[ni];
        v = v > 0.f ? v : 0.f;
        p += v * w2v[ni];
      }
      p += __shfl_xor(p, 1);
      p += __shfl_xor(p, 2);
      p += __shfl_xor(p, 4);
      p += __shfl_xor(p, 8);
      if (fr == 0) {
        const int gm = m0 + wm + mi * 16 + fq * 4 + r;
        part[(size_t)j * B_ROWS + gm] = p;
      }
    }
  }
}

// ---------------------------------------------------------------------------
// Final: sum partials, sigmoid, broadcast to out [3, B, 9]. 1 thread/row.
// ---------------------------------------------------------------------------
__global__ __launch_bounds__(256) void final_out(
    const float* __restrict__ part,
    const float* __restrict__ bc2, const float* __restrict__ bt2,
    const float* __restrict__ bk2, float* __restrict__ out) {
  const int row = blockIdx.x * 256 + threadIdx.x;
  float sc = 0.f, st = 0.f, sk = 0.f;
#pragma unroll
  for (int j = 0; j < 8; ++j)  sc += part[(size_t)j * B_ROWS + row];
#pragma unroll
  for (int j = 8; j < 16; ++j) st += part[(size_t)j * B_ROWS + row];
#pragma unroll
  for (int j = 16; j < 32; ++j) sk += part[(size_t)j * B_ROWS + row];
  const float cv = 1.f / (1.f + expf(-(sc + bc2[0])));
  const float tv = 1.f / (1.f + expf(-(st + bt2[0])));
  const float kv = 1.f / (1.f + expf(-(sk + bk2[0])));
  float* o0 = out + (size_t)row * N_AG;
  float* o1 = out + (size_t)(B_ROWS + row) * N_AG;
  float* o2 = out + (size_t)(2 * B_ROWS + row) * N_AG;
#pragma unroll
  for (int a = 0; a < N_AG; ++a) { o0[a] = cv; o1[a] = tv; o2[a] = kv; }
}

// ---------------------------------------------------------------------------
extern "C" void kernel_launch(void* const* d_in, const int* in_sizes, int n_in,
                              void* d_out, int out_size, void* d_ws, size_t ws_size,
                              hipStream_t stream) {
  const float* obs = (const float*)d_in[0];
  // d_in[1] agent_positions: unused (outputs don't depend on it)
  const float* W1  = (const float*)d_in[2];
  const float* b1  = (const float*)d_in[3];
  const float* W2  = (const float*)d_in[4];
  const float* b2  = (const float*)d_in[5];
  const float* Wc1 = (const float*)d_in[6];
  const float* bc1 = (const float*)d_in[7];
  const float* Wc2 = (const float*)d_in[8];
  const float* bc2 = (const float*)d_in[9];
  const float* Wt1 = (const float*)d_in[10];
  const float* bt1 = (const float*)d_in[11];
  const float* Wt2 = (const float*)d_in[12];
  const float* bt2 = (const float*)d_in[13];
  const float* Wk1 = (const float*)d_in[14];
  const float* bk1 = (const float*)d_in[15];
  const float* Wk2 = (const float*)d_in[16];
  const float* bk2 = (const float*)d_in[17];
  float* out = (float*)d_out;

  // Workspace layout. PART aliases obs_f (disjoint lifetimes).
  char* ws = (char*)d_ws;
  unsigned short* obs_f   = (unsigned short*)(ws + 0);         // 16 MB frag-major
  float*          PART    = (float*)(ws + 0);                  // 2 MB (alias)
  unsigned short* W1f     = (unsigned short*)(ws + 16777216);  // 1 MB  frag-major
  unsigned short* W2f     = (unsigned short*)(ws + 17825792);  // 2 MB  frag-major
  unsigned short* WHf     = (unsigned short*)(ws + 19922944);  // 4 MB  frag-major
  float*          bias2048= (float*)(ws + 24117248);           // 8 KB
  float*          w2cat   = (float*)(ws + 24125440);           // 8 KB
  unsigned short* G1      = (unsigned short*)(ws + 24330240);  // 32 MB frag-major
  unsigned short* G       = (unsigned short*)(ws + 57884672);  // 32 MB frag-major

  prep_all<<<7688, 256, 0, stream>>>(obs, W1, W2, Wc1, Wt1, Wk1,
                                     bc1, bt1, bk1, Wc2, Wt2, Wk2,
                                     obs_f, W1f, W2f, WHf, bias2048, w2cat);

  gemm_bias_relu<512, 8><<<1024, 256, 0, stream>>>(obs_f, W1f, b1, G1);
  gemm_bias_relu<1024, 8><<<1024, 256, 0, stream>>>(G1, W2f, b2, G);

  gemm_heads_fused<1024, 16><<<2048, 256, 0, stream>>>(G, WHf, bias2048, w2cat, PART);

  final_out<<<B_ROWS / 256, 256, 0, stream>>>(PART, bc2, bt2, bk2, out);
}

// Round 10
// 251.165 us; speedup vs baseline: 1.4386x; 1.4386x over previous
//
#include <hip/hip_runtime.h>
#include <hip/hip_bf16.h>

// Problem constants
#define B_ROWS 16384
#define OBS_D  512
#define H_D    1024
#define N_AG   9

typedef __attribute__((ext_vector_type(8))) short short8;
typedef __attribute__((ext_vector_type(4))) float floatx4;

__device__ __forceinline__ unsigned short f_to_bf_raw(float f) {
  union { float f; unsigned u; } c; c.f = f;
  unsigned u = c.u;
  u = u + 0x7FFF + ((u >> 16) & 1);   // round-to-nearest-even
  return (unsigned short)(u >> 16);
}

// Fragment-major WEIGHT layout (B operand only; A stays row-major):
//   frag_tile = (n>>4)*KT32 + (k>>5)
//   lane      = (n&15) | (((k>>3)&3)<<4)
//   j         = k&7
// offset (bf16 units) = (frag_tile*64 + lane)*8 + j
// -> a wave's B-frag load is base + lane*16: one coalesced 1KB dwordx4 line.
__device__ __forceinline__ size_t frag_off(int n, int k, int KT32) {
  const int ft = (n >> 4) * KT32 + (k >> 5);
  const int ln = (n & 15) | (((k >> 3) & 3) << 4);
  return ((size_t)ft * 64 + ln) * 8 + (k & 7);
}

// ---------------------------------------------------------------------------
// Mega-prep (round-8 version): obs cast row-major, W1f/W2f/WHf frag-major
// (WH = [Wc1|Wt1|Wk1fold]), bias2048/w2cat concat. Branch block-uniform.
// Grid: [0,4096) obs | [4096,4608) W1f | [4608,5632) W2f |
//       [5632,7680) WHf | [7680,7688) vecs
// ---------------------------------------------------------------------------
__global__ __launch_bounds__(256) void prep_all(
    const float* __restrict__ obs,
    const float* __restrict__ W1, const float* __restrict__ W2,
    const float* __restrict__ Wc1, const float* __restrict__ Wt1,
    const float* __restrict__ Wk1,
    const float* __restrict__ bc1, const float* __restrict__ bt1,
    const float* __restrict__ bk1,
    const float* __restrict__ Wc2, const float* __restrict__ Wt2,
    const float* __restrict__ Wk2,
    unsigned short* __restrict__ obs_bf,
    unsigned short* __restrict__ W1f, unsigned short* __restrict__ W2f,
    unsigned short* __restrict__ WHf,
    float* __restrict__ bias2048, float* __restrict__ w2cat) {
  __shared__ float t[32][33];
  const int bx  = blockIdx.x;
  const int tid = threadIdx.x;

  if (bx < 4096) {                       // obs fp32 -> bf16, 8 elems/thread
    int i = (bx * 256 + tid) * 8;
    float4 a = *(const float4*)(obs + i);
    float4 b = *(const float4*)(obs + i + 4);
    short8 o;
    o[0] = (short)f_to_bf_raw(a.x); o[1] = (short)f_to_bf_raw(a.y);
    o[2] = (short)f_to_bf_raw(a.z); o[3] = (short)f_to_bf_raw(a.w);
    o[4] = (short)f_to_bf_raw(b.x); o[5] = (short)f_to_bf_raw(b.y);
    o[6] = (short)f_to_bf_raw(b.z); o[7] = (short)f_to_bf_raw(b.w);
    *(short8*)(obs_bf + i) = o;
    return;
  }

  const int tx = tid & 31;
  const int ty = tid >> 5;   // 0..7

  if (bx < 4608) {                       // W1 [512,1024] -> W1f (K=512,KT32=16)
    const int tt = bx - 4096;
    const int k0 = (tt & 15) * 32;
    const int n0 = (tt >> 4) * 32;
#pragma unroll
    for (int i = ty; i < 32; i += 8)
      t[i][tx] = W1[(size_t)(k0 + i) * 1024 + n0 + tx];
    __syncthreads();
#pragma unroll
    for (int i = ty; i < 32; i += 8)
      W1f[frag_off(n0 + i, k0 + tx, 16)] = f_to_bf_raw(t[tx][i]);
    return;
  }

  if (bx < 5632) {                       // W2 [1024,1024] -> W2f (KT32=32)
    const int tt = bx - 4608;
    const int k0 = (tt & 31) * 32;
    const int n0 = (tt >> 5) * 32;
#pragma unroll
    for (int i = ty; i < 32; i += 8)
      t[i][tx] = W2[(size_t)(k0 + i) * 1024 + n0 + tx];
    __syncthreads();
#pragma unroll
    for (int i = ty; i < 32; i += 8)
      W2f[frag_off(n0 + i, k0 + tx, 32)] = f_to_bf_raw(t[tx][i]);
    return;
  }

  if (bx < 7680) {                       // WHf [2048 n,1024 k] (KT32=32)
    const int tt = bx - 5632;
    const int k0 = (tt & 31) * 32;
    const int n0 = (tt >> 5) * 32;       // region-uniform per block
#pragma unroll
    for (int i = ty; i < 32; i += 8) {
      const int n = n0 + tx;
      float v;
      if (n0 < 512)
        v = Wc1[(size_t)(k0 + i) * 512 + n];
      else if (n0 < 1024)
        v = Wt1[(size_t)(k0 + i) * 512 + (n - 512)];
      else
        v = Wk1[(size_t)(k0 + i) * 1024 + (n - 1024)]
          + Wk1[(size_t)(k0 + i + 1024) * 1024 + (n - 1024)];
      t[i][tx] = v;
    }
    __syncthreads();
#pragma unroll
    for (int i = ty; i < 32; i += 8)
      WHf[frag_off(n0 + i, k0 + tx, 32)] = f_to_bf_raw(t[tx][i]);
    return;
  }

  {                                      // bias2048 / w2cat
    int n = (bx - 7680) * 256 + tid;
    float b, w;
    if (n < 512)       { b = bc1[n];        w = Wc2[n]; }
    else if (n < 1024) { b = bt1[n - 512];  w = Wt2[n - 512]; }
    else               { b = bk1[n - 1024]; w = Wk2[n - 1024]; }
    bias2048[n] = b;
    w2cat[n] = w;
  }
}

// ===========================================================================
// GEMM core v9: 128x128 tile, BK=64, ONE barrier per 64-K iteration.
//  - A: row-major global -> LDS via global_load_lds, TRIPLE-buffered
//    (3 x 16 KB), DMA prefetch distance 2 -> each DMA has a full iteration
//    in flight before its drain. Swizzle for 128B rows: 16B-chunk c of row r
//    stored at slot c ^ (r&7) (global-side permute; DMA dest stays
//    wave-uniform + lane*16). Frag reads: 2 rows/bank-group per 16-lane
//    phase = free (m136; round-8's analogous pattern measured 0 conflicts).
//  - B: frag-major global (L2-hot weights), coalesced 1KB dwordx4 frag
//    loads, register prefetch distance 1 (round-8 proven).
//  - 32 MFMA per wave per iter: per-iter overhead (barrier drain, ds_read
//    latency) amortized over 2x the compute of round-8's BK=32.
// K template constant -> full unroll -> all buffer/frag indices compile-time
// (round-6 lesson: runtime-indexed arrays demote to scratch).
// Round-9 lesson: A must be LDS-shared between waves (direct per-wave global
// A doubled FETCH_SIZE and lost).
// ===========================================================================
#define GLD_LDS(gp, lp)                                                        \
  __builtin_amdgcn_global_load_lds(                                            \
      (const __attribute__((address_space(1))) void*)(gp),                     \
      (__attribute__((address_space(3))) void*)(lp), 16, 0, 0)

#define GEMM_CORE_V9(ACC_DECL)                                                 \
  __shared__ __align__(16) unsigned short As[3][128 * 64];  /* 48 KB */        \
  const int tid  = threadIdx.x;                                                \
  const int lane = tid & 63;                                                   \
  const int wave = tid >> 6;                                                   \
  const int m0 = blockIdx.x * 128;                                             \
  const int n0 = blockIdx.y * 128;                                             \
  const int wm = (wave & 1) * 64;                                              \
  const int wn = (wave >> 1) * 64;                                             \
  const int fr = lane & 15;                                                    \
  const int fq = lane >> 4;                                                    \
  ACC_DECL;                                                                    \
  constexpr int KT   = K >> 6;     /* BK=64 iterations      */                 \
  constexpr int KT32 = K >> 5;     /* 32-wide k-tiles (B)   */                 \
  const size_t rowb = (size_t)K * 2;                                           \
  const int srow8  = lane >> 3;                 /* 0..7 row in 8-row group */  \
  const int schunk = (lane & 7) ^ srow8;        /* swizzled global chunk   */  \
  const char* gA = (const char*)A + (size_t)(m0 + wave * 32 + srow8) * rowb    \
                   + schunk * 16;                                              \
  char* lA = (char*)&As[0][0] + wave * 4096 + lane * 16;                       \
  const unsigned short* gB =                                                   \
      Bf + ((size_t)(((n0 + wn) >> 4) * KT32) * 64 + lane) * 8;                \
  const int fsA = (wm + fr) * 128;                                             \
  const int sl0 = ((fq)     ^ (fr & 7)) * 16;                                  \
  const int sl1 = ((4 + fq) ^ (fr & 7)) * 16;                                  \
  short8 FbP[2][2][4];                                                         \
  /* prologue: DMA tiles 0,1 -> bufs 0,1; B-frags for iter 0 */                \
  _Pragma("unroll")                                                            \
  for (int j = 0; j < 4; ++j)                                                  \
    GLD_LDS(gA + (size_t)j * 8 * rowb, lA + j * 1024);                         \
  _Pragma("unroll")                                                            \
  for (int j = 0; j < 4; ++j)                                                  \
    GLD_LDS(gA + 128 + (size_t)j * 8 * rowb,                                   \
            (char*)&As[1][0] + wave * 4096 + lane * 16 + j * 1024);            \
  _Pragma("unroll")                                                            \
  for (int s = 0; s < 2; ++s)                                                  \
    _Pragma("unroll")                                                          \
    for (int ni = 0; ni < 4; ++ni)                                             \
      FbP[0][s][ni] = *(const short8*)(gB + ((size_t)ni * KT32 + s) * 512);    \
  _Pragma("unroll")                                                            \
  for (int k = 0; k < KT; ++k) {       /* constexpr bound -> full unroll */    \
    __syncthreads();   /* drains DMA(k+1) (one full iter in flight) */         \
    if (k + 2 < KT) {                                                          \
      char* d = (char*)&As[(k + 2) % 3][0] + wave * 4096 + lane * 16;          \
      const char* g = gA + (size_t)(k + 2) * 128;                              \
      _Pragma("unroll")                                                        \
      for (int j = 0; j < 4; ++j)                                              \
        GLD_LDS(g + (size_t)j * 8 * rowb, d + j * 1024);                       \
    }                                                                          \
    if (k + 1 < KT) {                                                          \
      _Pragma("unroll")                                                        \
      for (int s = 0; s < 2; ++s)                                              \
        _Pragma("unroll")                                                      \
        for (int ni = 0; ni < 4; ++ni)                                         \
          FbP[(k + 1) & 1][s][ni] = *(const short8*)                           \
              (gB + ((size_t)ni * KT32 + 2 * (k + 1) + s) * 512);              \
    }                                                                          \
    const char* bA = (const char*)&As[k % 3][0];                               \
    short8 Fa0[4], Fa1[4];                                                     \
    _Pragma("unroll")                                                          \
    for (int mi = 0; mi < 4; ++mi)                                             \
      Fa0[mi] = *(const short8*)(bA + fsA + mi * 2048 + sl0);                  \
    _Pragma("unroll")                                                          \
    for (int mi = 0; mi < 4; ++mi)                                             \
      Fa1[mi] = *(const short8*)(bA + fsA + mi * 2048 + sl1);                  \
    _Pragma("unroll")                                                          \
    for (int mi = 0; mi < 4; ++mi)                                             \
      _Pragma("unroll")                                                        \
      for (int ni = 0; ni < 4; ++ni)                                           \
        acc[mi][ni] = __builtin_amdgcn_mfma_f32_16x16x32_bf16(                 \
            Fa0[mi], FbP[k & 1][0][ni], acc[mi][ni], 0, 0, 0);                 \
    _Pragma("unroll")                                                          \
    for (int mi = 0; mi < 4; ++mi)                                             \
      _Pragma("unroll")                                                        \
      for (int ni = 0; ni < 4; ++ni)                                           \
        acc[mi][ni] = __builtin_amdgcn_mfma_f32_16x16x32_bf16(                 \
            Fa1[mi], FbP[k & 1][1][ni], acc[mi][ni], 0, 0, 0);                 \
  }

#define ACC_INIT                                                               \
  floatx4 acc[4][4];                                                           \
  _Pragma("unroll")                                                            \
  for (int i = 0; i < 4; ++i)                                                  \
    _Pragma("unroll")                                                          \
    for (int j = 0; j < 4; ++j) acc[i][j] = (floatx4){0.f, 0.f, 0.f, 0.f}

// ---------------------------------------------------------------------------
// GEMM: C = relu(A @ B^T + bias), bf16 out (row-major). Bf frag-major.
// ---------------------------------------------------------------------------
template <int K>
__global__ __launch_bounds__(256, 2) void gemm_bias_relu(
    const unsigned short* __restrict__ A,
    const unsigned short* __restrict__ Bf,
    const float* __restrict__ bias,
    unsigned short* __restrict__ C,
    int M, int N) {
  GEMM_CORE_V9(ACC_INIT)

  // Epilogue: C/D layout col=lane&15, row=(lane>>4)*4+reg
#pragma unroll
  for (int ni = 0; ni < 4; ++ni) {
    const int gn = n0 + wn + ni * 16 + fr;
    const float bv = bias[gn];
#pragma unroll
    for (int mi = 0; mi < 4; ++mi) {
#pragma unroll
      for (int r = 0; r < 4; ++r) {
        const int gm = m0 + wm + mi * 16 + fq * 4 + r;
        float v = acc[mi][ni][r] + bv;
        v = v > 0.f ? v : 0.f;
        C[(size_t)gm * N + gn] = f_to_bf_raw(v);
      }
    }
  }
}

// ---------------------------------------------------------------------------
// Fused heads GEMM: relu(G @ WH^T + bias2048) dotted with w2cat in-register,
// non-atomic partials part[j][row], j = blockIdx.y*2 + wave_half in [0,32).
// j 0..7 coverage, 8..15 tracking, 16..31 cooperation.
// ---------------------------------------------------------------------------
template <int K>
__global__ __launch_bounds__(256, 2) void gemm_heads_fused(
    const unsigned short* __restrict__ A,    // G row-major [B,1024]
    const unsigned short* __restrict__ Bf,   // WHf frag-major [2048,1024]
    const float* __restrict__ bias,          // bias2048
    const float* __restrict__ w2,            // w2cat
    float* __restrict__ part,                // [32][B_ROWS]
    int M, int N) {
  GEMM_CORE_V9(ACC_INIT)

  const int j = blockIdx.y * 2 + (wave >> 1);
  float w2v[4], bv[4];
#pragma unroll
  for (int ni = 0; ni < 4; ++ni) {
    const int gn = n0 + wn + ni * 16 + fr;
    w2v[ni] = w2[gn];
    bv[ni]  = bias[gn];
  }
#pragma unroll
  for (int mi = 0; mi < 4; ++mi) {
#pragma unroll
    for (int r = 0; r < 4; ++r) {
      float p = 0.f;
#pragma unroll
      for (int ni = 0; ni < 4; ++ni) {
        float v = acc[mi][ni][r] + bv[ni];
        v = v > 0.f ? v : 0.f;
        p += v * w2v[ni];
      }
      p += __shfl_xor(p, 1);
      p += __shfl_xor(p, 2);
      p += __shfl_xor(p, 4);
      p += __shfl_xor(p, 8);
      if (fr == 0) {
        const int gm = m0 + wm + mi * 16 + fq * 4 + r;
        part[(size_t)j * B_ROWS + gm] = p;
      }
    }
  }
}

// ---------------------------------------------------------------------------
// Final: sum partials, sigmoid, broadcast to out [3, B, 9]. 1 thread/row.
// ---------------------------------------------------------------------------
__global__ __launch_bounds__(256) void final_out(
    const float* __restrict__ part,
    const float* __restrict__ bc2, const float* __restrict__ bt2,
    const float* __restrict__ bk2, float* __restrict__ out) {
  const int row = blockIdx.x * 256 + threadIdx.x;
  float sc = 0.f, st = 0.f, sk = 0.f;
#pragma unroll
  for (int j = 0; j < 8; ++j)  sc += part[(size_t)j * B_ROWS + row];
#pragma unroll
  for (int j = 8; j < 16; ++j) st += part[(size_t)j * B_ROWS + row];
#pragma unroll
  for (int j = 16; j < 32; ++j) sk += part[(size_t)j * B_ROWS + row];
  const float cv = 1.f / (1.f + expf(-(sc + bc2[0])));
  const float tv = 1.f / (1.f + expf(-(st + bt2[0])));
  const float kv = 1.f / (1.f + expf(-(sk + bk2[0])));
  float* o0 = out + (size_t)row * N_AG;
  float* o1 = out + (size_t)(B_ROWS + row) * N_AG;
  float* o2 = out + (size_t)(2 * B_ROWS + row) * N_AG;
#pragma unroll
  for (int a = 0; a < N_AG; ++a) { o0[a] = cv; o1[a] = tv; o2[a] = kv; }
}

// ---------------------------------------------------------------------------
extern "C" void kernel_launch(void* const* d_in, const int* in_sizes, int n_in,
                              void* d_out, int out_size, void* d_ws, size_t ws_size,
                              hipStream_t stream) {
  const float* obs = (const float*)d_in[0];
  // d_in[1] agent_positions: unused (outputs don't depend on it)
  const float* W1  = (const float*)d_in[2];
  const float* b1  = (const float*)d_in[3];
  const float* W2  = (const float*)d_in[4];
  const float* b2  = (const float*)d_in[5];
  const float* Wc1 = (const float*)d_in[6];
  const float* bc1 = (const float*)d_in[7];
  const float* Wc2 = (const float*)d_in[8];
  const float* bc2 = (const float*)d_in[9];
  const float* Wt1 = (const float*)d_in[10];
  const float* bt1 = (const float*)d_in[11];
  const float* Wt2 = (const float*)d_in[12];
  const float* bt2 = (const float*)d_in[13];
  const float* Wk1 = (const float*)d_in[14];
  const float* bk1 = (const float*)d_in[15];
  const float* Wk2 = (const float*)d_in[16];
  const float* bk2 = (const float*)d_in[17];
  float* out = (float*)d_out;

  // Workspace layout. PART aliases obs_bf (disjoint lifetimes).
  char* ws = (char*)d_ws;
  unsigned short* obs_bf  = (unsigned short*)(ws + 0);         // 16 MB
  float*          PART    = (float*)(ws + 0);                  // 2 MB (alias)
  unsigned short* W1f     = (unsigned short*)(ws + 16777216);  // 1 MB  frag-major
  unsigned short* W2f     = (unsigned short*)(ws + 17825792);  // 2 MB  frag-major
  unsigned short* WHf     = (unsigned short*)(ws + 19922944);  // 4 MB  frag-major
  float*          bias2048= (float*)(ws + 24117248);           // 8 KB
  float*          w2cat   = (float*)(ws + 24125440);           // 8 KB
  unsigned short* G1      = (unsigned short*)(ws + 24330240);  // 32 MB
  unsigned short* G       = (unsigned short*)(ws + 57884672);  // 32 MB

  prep_all<<<7688, 256, 0, stream>>>(obs, W1, W2, Wc1, Wt1, Wk1,
                                     bc1, bt1, bk1, Wc2, Wt2, Wk2,
                                     obs_bf, W1f, W2f, WHf, bias2048, w2cat);

  gemm_bias_relu<512><<<dim3(128, 8), 256, 0, stream>>>(obs_bf, W1f, b1, G1, B_ROWS, 1024);
  gemm_bias_relu<1024><<<dim3(128, 8), 256, 0, stream>>>(G1, W2f, b2, G, B_ROWS, 1024);

  gemm_heads_fused<1024><<<dim3(128, 16), 256, 0, stream>>>(G, WHf, bias2048, w2cat, PART,
                                                            B_ROWS, 2048);

  final_out<<<B_ROWS / 256, 256, 0, stream>>>(PART, bc2, bt2, bk2, out);
}